// Round 1
// baseline (1308.680 us; speedup 1.0000x reference)
//
#include <hip/hip_runtime.h>
#include <stdint.h>

#define E_ 8
#define S_ 8192
#define H_ 2048
#define F_ 8192
#define C_ 1024
#define OUTN (S_*H_)

typedef __bf16 bf16x8 __attribute__((ext_vector_type(8)));
typedef float  f32x4  __attribute__((ext_vector_type(4)));
typedef unsigned short us8 __attribute__((ext_vector_type(8)));

__device__ __forceinline__ unsigned short f2bf(float f) {
    union { float f; unsigned u; } v; v.f = f;
    unsigned r = (v.u + 0x7FFFu + ((v.u >> 16) & 1u)) >> 16;
    return (unsigned short)r;
}

// async global->LDS, 16B per lane; LDS dest must be wave-uniform base (HW adds lane*16)
__device__ __forceinline__ void gload16(const void* g, void* l) {
    auto gp = (const __attribute__((address_space(1))) void*)(unsigned long long)(uintptr_t)g;
    auto lp = (__attribute__((address_space(3))) void*)(unsigned int)(uintptr_t)l;
    __builtin_amdgcn_global_load_lds(gp, lp, 16, 0, 0);
}

// ---------------- zero d_out ----------------
__global__ void zero_kernel(float* __restrict__ o, int n) {
    int i = blockIdx.x * blockDim.x + threadIdx.x;
    int st = gridDim.x * blockDim.x;
    for (; i < n; i += st) o[i] = 0.f;
}

// ---------------- transpose + fp32->bf16: dst[e][n][k] = src[e][k][n] ----------------
__global__ __launch_bounds__(256)
void transpose_cvt(const float* __restrict__ src, unsigned short* __restrict__ dst,
                   int R, int Cc)   // R = K-dim rows of src, Cc = N-dim cols of src
{
    __shared__ float t[64][65];
    int tilesR = R >> 6, tilesC = Cc >> 6;
    int per_e = tilesR * tilesC;
    int bid = blockIdx.x;
    int e  = bid / per_e;
    int rm = bid - e * per_e;
    int tc = rm / tilesR;
    int tr = rm - tc * tilesR;

    const float* s = src + (size_t)e * R * Cc + (size_t)(tr * 64) * Cc + tc * 64;
    int tid = threadIdx.x;
    int rr = tid >> 4;
    int cc = (tid & 15) << 2;
#pragma unroll
    for (int i = 0; i < 4; i++) {
        float4 v = *(const float4*)(s + (size_t)(rr + i * 16) * Cc + cc);
        t[rr + i * 16][cc + 0] = v.x;
        t[rr + i * 16][cc + 1] = v.y;
        t[rr + i * 16][cc + 2] = v.z;
        t[rr + i * 16][cc + 3] = v.w;
    }
    __syncthreads();
    int nl = tid >> 2;
    int kq = (tid & 3) << 4;
    us8 o0, o1;
#pragma unroll
    for (int i = 0; i < 8; i++) o0[i] = f2bf(t[kq + i][nl]);
#pragma unroll
    for (int i = 0; i < 8; i++) o1[i] = f2bf(t[kq + 8 + i][nl]);
    unsigned short* d = dst + (size_t)e * R * Cc + (size_t)(tc * 64 + nl) * R + tr * 64 + kq;
    *reinterpret_cast<us8*>(d)     = o0;
    *reinterpret_cast<us8*>(d + 8) = o1;
}

// ---------------- gating: logits = x @ wg, softmax, argmax ----------------
__global__ __launch_bounds__(256)
void gating_kernel(const float* __restrict__ x, const float* __restrict__ wg,
                   int* __restrict__ expert_id, float* __restrict__ gate_tok,
                   float* __restrict__ gates_all)
{
    int lane = threadIdx.x & 63;
    int wid  = threadIdx.x >> 6;
    int s = blockIdx.x * 4 + wid;
    const float* xs = x + (size_t)s * H_;
    float p[8];
#pragma unroll
    for (int j = 0; j < 8; j++) p[j] = 0.f;
    for (int h = lane; h < H_; h += 64) {
        float xv = xs[h];
        const float4* w4 = (const float4*)(wg + (size_t)h * 8);
        float4 a = w4[0], b = w4[1];
        p[0] += xv * a.x; p[1] += xv * a.y; p[2] += xv * a.z; p[3] += xv * a.w;
        p[4] += xv * b.x; p[5] += xv * b.y; p[6] += xv * b.z; p[7] += xv * b.w;
    }
#pragma unroll
    for (int off = 32; off; off >>= 1) {
#pragma unroll
        for (int j = 0; j < 8; j++) p[j] += __shfl_xor(p[j], off);
    }
    if (lane == 0) {
        float mx = p[0];
#pragma unroll
        for (int j = 1; j < 8; j++) mx = fmaxf(mx, p[j]);
        float ex[8], sum = 0.f;
#pragma unroll
        for (int j = 0; j < 8; j++) { ex[j] = expf(p[j] - mx); sum += ex[j]; }
        float inv = 1.f / sum;
        int am = 0; float best = p[0];
#pragma unroll
        for (int j = 1; j < 8; j++) if (p[j] > best) { best = p[j]; am = j; }
        expert_id[s] = am;
        gate_tok[s]  = expf(best - mx) * inv;
        float* ga = gates_all + (size_t)s * 8;
#pragma unroll
        for (int j = 0; j < 8; j++) ga[j] = ex[j] * inv;
    }
}

// ---------------- single-block capacity scan + l_aux + exp_counts ----------------
__global__ __launch_bounds__(1024)
void scan_kernel(const int* __restrict__ expert_id,
                 const float* __restrict__ gate_tok,
                 const float* __restrict__ gates_all,
                 int* __restrict__ token_slot,
                 float* __restrict__ gate_slot,
                 float* __restrict__ out_tail)
{
    __shared__ unsigned long long wt0[16], wt1[16];
    __shared__ unsigned long long tot0s, tot1s;
    __shared__ float red[1024 * 8];

    int tid = threadIdx.x;
    for (int i = tid; i < E_ * C_; i += 1024) token_slot[i] = -1;

    int ids[8];
#pragma unroll
    for (int j = 0; j < 8; j++) ids[j] = expert_id[tid * 8 + j];

    unsigned long long c0 = 0, c1 = 0;
#pragma unroll
    for (int j = 0; j < 8; j++) {
        int e = ids[j];
        unsigned long long inc = 1ull << ((e & 3) * 16);
        if (e < 4) c0 += inc; else c1 += inc;
    }
    unsigned long long s0 = c0, s1 = c1;
    int lane = tid & 63, w = tid >> 6;
#pragma unroll
    for (int off = 1; off < 64; off <<= 1) {
        unsigned long long t0 = __shfl_up(s0, off);
        unsigned long long t1 = __shfl_up(s1, off);
        if (lane >= off) { s0 += t0; s1 += t1; }
    }
    if (lane == 63) { wt0[w] = s0; wt1[w] = s1; }
    __syncthreads();
    unsigned long long off0 = 0, off1 = 0;
    for (int i = 0; i < w; i++) { off0 += wt0[i]; off1 += wt1[i]; }
    unsigned long long p0 = off0 + s0 - c0;
    unsigned long long p1 = off1 + s1 - c1;

#pragma unroll
    for (int j = 0; j < 8; j++) {
        int stok = tid * 8 + j;
        int e = ids[j];
        int sh = (e & 3) * 16;
        int slot = (int)(((e < 4 ? p0 : p1) >> sh) & 0xFFFFull);
        if (slot < C_) {
            token_slot[e * C_ + slot] = stok;
            gate_slot[e * C_ + slot]  = gate_tok[stok];
        }
        if (e < 4) p0 += 1ull << sh; else p1 += 1ull << sh;
    }
    if (tid == 1023) { tot0s = off0 + s0; tot1s = off1 + s1; }

    float me[8];
#pragma unroll
    for (int e2 = 0; e2 < 8; e2++) me[e2] = 0.f;
#pragma unroll
    for (int j = 0; j < 8; j++) {
        const float* ga = gates_all + (size_t)(tid * 8 + j) * 8;
#pragma unroll
        for (int e2 = 0; e2 < 8; e2++) me[e2] += ga[e2];
    }
#pragma unroll
    for (int e2 = 0; e2 < 8; e2++) red[tid * 8 + e2] = me[e2];
    __syncthreads();
    for (int st = 512; st > 0; st >>= 1) {
        if (tid < st) {
#pragma unroll
            for (int e2 = 0; e2 < 8; e2++) red[tid * 8 + e2] += red[(tid + st) * 8 + e2];
        }
        __syncthreads();
    }
    if (tid == 0) {
        float laux = 0.f;
#pragma unroll
        for (int e2 = 0; e2 < 8; e2++) {
            unsigned long long tv = (e2 < 4) ? tot0s : tot1s;
            float cnt = (float)((tv >> ((e2 & 3) * 16)) & 0xFFFFull);
            laux += red[e2] * cnt;
            out_tail[1 + e2] = cnt;
        }
        out_tail[0] = laux * (8.f / (8192.f * 8192.f));
    }
}

// ---------------- gather dispatched rows (fp32 -> bf16) ----------------
__global__ __launch_bounds__(256)
void gather_kernel(const float* __restrict__ x, const int* __restrict__ token_slot,
                   unsigned short* __restrict__ disp)
{
    int slot = blockIdx.x;
    int tok = token_slot[slot];
    int t = threadIdx.x;
    us8* d = reinterpret_cast<us8*>(disp + (size_t)slot * H_ + t * 8);
    if (tok < 0) {
        us8 z;
#pragma unroll
        for (int i = 0; i < 8; i++) z[i] = 0;
        *d = z;
        return;
    }
    const float4* s4 = (const float4*)(x + (size_t)tok * H_ + t * 8);
    float4 a = s4[0], b = s4[1];
    us8 o;
    o[0] = f2bf(a.x); o[1] = f2bf(a.y); o[2] = f2bf(a.z); o[3] = f2bf(a.w);
    o[4] = f2bf(b.x); o[5] = f2bf(b.y); o[6] = f2bf(b.z); o[7] = f2bf(b.w);
    *d = o;
}

// ---------------- bf16 MFMA GEMM, B pre-transposed [E][N][K] ----------------
// EPI 0: hout = gelu(A@B + bias) as bf16   (A = dispatched, B = w1t)
// EPI 1: scatter fout[tok] = gate * (A@B + bias)   (A = h, B = w2t)
template<int EPI>
__global__ __launch_bounds__(256)
void gemm_bt(const unsigned short* __restrict__ A,
             const unsigned short* __restrict__ B,
             const float* __restrict__ bias,
             unsigned short* __restrict__ hout,
             float* __restrict__ fout,
             const int* __restrict__ token_slot,
             const float* __restrict__ gate_slot,
             int K, int N, int Mtiles, int Ntiles)
{
    __shared__ unsigned short lA[128 * 32];
    __shared__ unsigned short lB[128 * 32];

    int nwg = gridDim.x;
    int bid = blockIdx.x;
    int cpx = nwg >> 3;                       // grids are multiples of 8
    int wg = (bid & 7) * cpx + (bid >> 3);    // XCD-contiguous logical id

    int per_e = Mtiles * Ntiles;
    int e  = wg / per_e;
    int r  = wg - e * per_e;
    int nt = r / Mtiles;
    int mt = r - nt * Mtiles;                 // m fastest: B-panel L2 reuse

    int tid  = threadIdx.x;
    int lane = tid & 63;
    int wid  = tid >> 6;
    int wr = wid >> 1, wc = wid & 1;

    const unsigned short* Ae = A + ((size_t)e * C_ + (size_t)mt * 128) * (size_t)K;
    const unsigned short* Be = B + ((size_t)e * N  + (size_t)nt * 128) * (size_t)K;

    int srow = wid * 16 + (lane >> 2);
    int scol = (lane & 3) * 16;
    const char* gA0 = (const char*)Ae + (size_t)srow * (size_t)(K * 2) + scol;
    const char* gA1 = gA0 + (size_t)64 * (size_t)(K * 2);
    const char* gB0 = (const char*)Be + (size_t)srow * (size_t)(K * 2) + scol;
    const char* gB1 = gB0 + (size_t)64 * (size_t)(K * 2);
    char* dA0 = (char*)lA + wid * 1024;
    char* dA1 = dA0 + 4096;
    char* dB0 = (char*)lB + wid * 1024;
    char* dB1 = dB0 + 4096;

    f32x4 acc[4][4];
    f32x4 zv = {0.f, 0.f, 0.f, 0.f};
#pragma unroll
    for (int i = 0; i < 4; i++) {
#pragma unroll
        for (int j = 0; j < 4; j++) acc[i][j] = zv;
    }

    int arow = wr * 64 + (lane & 15);
    int brow = wc * 64 + (lane & 15);
    int kof  = (lane >> 4) * 8;

    for (int k0 = 0; k0 < K; k0 += 32) {
        size_t kb = (size_t)k0 * 2;
        gload16(gA0 + kb, dA0);
        gload16(gA1 + kb, dA1);
        gload16(gB0 + kb, dB0);
        gload16(gB1 + kb, dB1);
        __syncthreads();

        bf16x8 af[4], bv[4];
#pragma unroll
        for (int mi = 0; mi < 4; mi++)
            af[mi] = *reinterpret_cast<const bf16x8*>(&lA[(arow + mi * 16) * 32 + kof]);
#pragma unroll
        for (int ni = 0; ni < 4; ni++)
            bv[ni] = *reinterpret_cast<const bf16x8*>(&lB[(brow + ni * 16) * 32 + kof]);
#pragma unroll
        for (int mi = 0; mi < 4; mi++) {
#pragma unroll
            for (int ni = 0; ni < 4; ni++)
                acc[mi][ni] = __builtin_amdgcn_mfma_f32_16x16x32_bf16(af[mi], bv[ni], acc[mi][ni], 0, 0, 0);
        }
        __syncthreads();
    }

    int rbase = wr * 64 + (lane >> 4) * 4;
    int cbase = wc * 64 + (lane & 15);

    if (EPI == 0) {
        size_t rowbase = (size_t)e * C_ + (size_t)mt * 128;
#pragma unroll
        for (int ni = 0; ni < 4; ni++) {
            int n = nt * 128 + cbase + ni * 16;
            float bb = bias[(size_t)e * N + n];
#pragma unroll
            for (int mi = 0; mi < 4; mi++) {
#pragma unroll
                for (int rr2 = 0; rr2 < 4; rr2++) {
                    int m = rbase + mi * 16 + rr2;
                    float v = acc[mi][ni][rr2] + bb;
                    float u = 0.7978845608028654f * (v + 0.044715f * v * v * v);
                    float gl = 0.5f * v * (1.0f + tanhf(u));
                    hout[(rowbase + (size_t)m) * (size_t)N + n] = f2bf(gl);
                }
            }
        }
    } else {
#pragma unroll
        for (int mi = 0; mi < 4; mi++) {
#pragma unroll
            for (int rr2 = 0; rr2 < 4; rr2++) {
                int c = mt * 128 + rbase + mi * 16 + rr2;
                int tok = token_slot[e * C_ + c];
                if (tok < 0) continue;
                float g = gate_slot[e * C_ + c];
#pragma unroll
                for (int ni = 0; ni < 4; ni++) {
                    int n = nt * 128 + cbase + ni * 16;
                    float v = (acc[mi][ni][rr2] + bias[(size_t)e * N + n]) * g;
                    fout[(size_t)tok * (size_t)N + n] = v;
                }
            }
        }
    }
}

extern "C" void kernel_launch(void* const* d_in, const int* in_sizes, int n_in,
                              void* d_out, int out_size, void* d_ws, size_t ws_size,
                              hipStream_t stream)
{
    const float* x   = (const float*)d_in[0];
    const float* wgp = (const float*)d_in[1];
    const float* w1  = (const float*)d_in[2];
    const float* b1  = (const float*)d_in[3];
    const float* w2  = (const float*)d_in[4];
    const float* b2  = (const float*)d_in[5];
    float* out = (float*)d_out;

    char* ws = (char*)d_ws;
    unsigned short* w1t  = (unsigned short*)(ws);                    // 268435456 B
    unsigned short* w2t  = (unsigned short*)(ws + 268435456ull);     // 268435456 B
    unsigned short* disp = (unsigned short*)(ws + 536870912ull);     //  33554432 B
    unsigned short* hbuf = (unsigned short*)(ws + 570425344ull);     // 134217728 B
    int*   expert_id  = (int*)  (ws + 704643072ull);                 // 32 KB
    float* gate_tok   = (float*)(ws + 704675840ull);                 // 32 KB
    float* gates_all  = (float*)(ws + 704708608ull);                 // 256 KB
    int*   token_slot = (int*)  (ws + 704970752ull);                 // 32 KB
    float* gate_slot  = (float*)(ws + 705003520ull);                 // 32 KB

    zero_kernel<<<4096, 256, 0, stream>>>(out, out_size);
    transpose_cvt<<<8 * 32 * 128, 256, 0, stream>>>(w1, w1t, 2048, 8192);
    transpose_cvt<<<8 * 128 * 32, 256, 0, stream>>>(w2, w2t, 8192, 2048);
    gating_kernel<<<2048, 256, 0, stream>>>(x, wgp, expert_id, gate_tok, gates_all);
    scan_kernel<<<1, 1024, 0, stream>>>(expert_id, gate_tok, gates_all, token_slot, gate_slot, out + OUTN);
    gather_kernel<<<8192, 256, 0, stream>>>(x, token_slot, disp);
    gemm_bt<0><<<4096, 256, 0, stream>>>(disp, w1t, b1, hbuf, nullptr, nullptr, nullptr, 2048, 8192, 8, 64);
    gemm_bt<1><<<1024, 256, 0, stream>>>(hbuf, w2t, b2, nullptr, out, token_slot, gate_slot, 8192, 2048, 8, 16);
}

// Round 2
// 854.823 us; speedup vs baseline: 1.5309x; 1.5309x over previous
//
#include <hip/hip_runtime.h>
#include <stdint.h>

#define E_ 8
#define S_ 8192
#define H_ 2048
#define F_ 8192
#define C_ 1024
#define OUTN (S_*H_)

typedef __bf16 bf16x8 __attribute__((ext_vector_type(8)));
typedef float  f32x4  __attribute__((ext_vector_type(4)));
typedef unsigned short us8 __attribute__((ext_vector_type(8)));

__device__ __forceinline__ unsigned short f2bf(float f) {
    union { float f; unsigned u; } v; v.f = f;
    unsigned r = (v.u + 0x7FFFu + ((v.u >> 16) & 1u)) >> 16;
    return (unsigned short)r;
}

__device__ __forceinline__ void gload16(const void* g, void* l) {
    auto gp = (const __attribute__((address_space(1))) void*)(unsigned long long)(uintptr_t)g;
    auto lp = (__attribute__((address_space(3))) void*)(unsigned int)(uintptr_t)l;
    __builtin_amdgcn_global_load_lds(gp, lp, 16, 0, 0);
}

#define SB() __builtin_amdgcn_sched_barrier(0)
#define BAR() do { SB(); __builtin_amdgcn_s_barrier(); SB(); } while(0)

// ---------------- zero d_out ----------------
__global__ void zero_kernel(float* __restrict__ o, int n) {
    int i = blockIdx.x * blockDim.x + threadIdx.x;
    int st = gridDim.x * blockDim.x;
    for (; i < n; i += st) o[i] = 0.f;
}

// ---------------- transpose + fp32->bf16: dst[e][n][k] = src[e][k][n] ----------------
__global__ __launch_bounds__(256)
void transpose_cvt(const float* __restrict__ src, unsigned short* __restrict__ dst,
                   int R, int Cc)
{
    __shared__ float t[64][65];
    int tilesR = R >> 6, tilesC = Cc >> 6;
    int per_e = tilesR * tilesC;
    int bid = blockIdx.x;
    int e  = bid / per_e;
    int rm = bid - e * per_e;
    int tc = rm / tilesR;
    int tr = rm - tc * tilesR;

    const float* s = src + (size_t)e * R * Cc + (size_t)(tr * 64) * Cc + tc * 64;
    int tid = threadIdx.x;
    int rr = tid >> 4;
    int cc = (tid & 15) << 2;
#pragma unroll
    for (int i = 0; i < 4; i++) {
        float4 v = *(const float4*)(s + (size_t)(rr + i * 16) * Cc + cc);
        t[rr + i * 16][cc + 0] = v.x;
        t[rr + i * 16][cc + 1] = v.y;
        t[rr + i * 16][cc + 2] = v.z;
        t[rr + i * 16][cc + 3] = v.w;
    }
    __syncthreads();
    int nl = tid >> 2;
    int kq = (tid & 3) << 4;
    us8 o0, o1;
#pragma unroll
    for (int i = 0; i < 8; i++) o0[i] = f2bf(t[kq + i][nl]);
#pragma unroll
    for (int i = 0; i < 8; i++) o1[i] = f2bf(t[kq + 8 + i][nl]);
    unsigned short* d = dst + (size_t)e * R * Cc + (size_t)(tc * 64 + nl) * R + tr * 64 + kq;
    *reinterpret_cast<us8*>(d)     = o0;
    *reinterpret_cast<us8*>(d + 8) = o1;
}

// ---------------- gating ----------------
__global__ __launch_bounds__(256)
void gating_kernel(const float* __restrict__ x, const float* __restrict__ wg,
                   int* __restrict__ expert_id, float* __restrict__ gate_tok,
                   float* __restrict__ gates_all)
{
    int lane = threadIdx.x & 63;
    int wid  = threadIdx.x >> 6;
    int s = blockIdx.x * 4 + wid;
    const float* xs = x + (size_t)s * H_;
    float p[8];
#pragma unroll
    for (int j = 0; j < 8; j++) p[j] = 0.f;
    for (int h = lane; h < H_; h += 64) {
        float xv = xs[h];
        const float4* w4 = (const float4*)(wg + (size_t)h * 8);
        float4 a = w4[0], b = w4[1];
        p[0] += xv * a.x; p[1] += xv * a.y; p[2] += xv * a.z; p[3] += xv * a.w;
        p[4] += xv * b.x; p[5] += xv * b.y; p[6] += xv * b.z; p[7] += xv * b.w;
    }
#pragma unroll
    for (int off = 32; off; off >>= 1) {
#pragma unroll
        for (int j = 0; j < 8; j++) p[j] += __shfl_xor(p[j], off);
    }
    if (lane == 0) {
        float mx = p[0];
#pragma unroll
        for (int j = 1; j < 8; j++) mx = fmaxf(mx, p[j]);
        float ex[8], sum = 0.f;
#pragma unroll
        for (int j = 0; j < 8; j++) { ex[j] = expf(p[j] - mx); sum += ex[j]; }
        float inv = 1.f / sum;
        int am = 0; float best = p[0];
#pragma unroll
        for (int j = 1; j < 8; j++) if (p[j] > best) { best = p[j]; am = j; }
        expert_id[s] = am;
        gate_tok[s]  = expf(best - mx) * inv;
        float* ga = gates_all + (size_t)s * 8;
#pragma unroll
        for (int j = 0; j < 8; j++) ga[j] = ex[j] * inv;
    }
}

// ---------------- single-block capacity scan + l_aux + exp_counts ----------------
__global__ __launch_bounds__(1024)
void scan_kernel(const int* __restrict__ expert_id,
                 const float* __restrict__ gate_tok,
                 const float* __restrict__ gates_all,
                 int* __restrict__ token_slot,
                 float* __restrict__ gate_slot,
                 float* __restrict__ out_tail)
{
    __shared__ unsigned long long wt0[16], wt1[16];
    __shared__ unsigned long long tot0s, tot1s;
    __shared__ float red[1024 * 8];

    int tid = threadIdx.x;
    for (int i = tid; i < E_ * C_; i += 1024) token_slot[i] = -1;

    int ids[8];
#pragma unroll
    for (int j = 0; j < 8; j++) ids[j] = expert_id[tid * 8 + j];

    unsigned long long c0 = 0, c1 = 0;
#pragma unroll
    for (int j = 0; j < 8; j++) {
        int e = ids[j];
        unsigned long long inc = 1ull << ((e & 3) * 16);
        if (e < 4) c0 += inc; else c1 += inc;
    }
    unsigned long long s0 = c0, s1 = c1;
    int lane = tid & 63, w = tid >> 6;
#pragma unroll
    for (int off = 1; off < 64; off <<= 1) {
        unsigned long long t0 = __shfl_up(s0, off);
        unsigned long long t1 = __shfl_up(s1, off);
        if (lane >= off) { s0 += t0; s1 += t1; }
    }
    if (lane == 63) { wt0[w] = s0; wt1[w] = s1; }
    __syncthreads();
    unsigned long long off0 = 0, off1 = 0;
    for (int i = 0; i < w; i++) { off0 += wt0[i]; off1 += wt1[i]; }
    unsigned long long p0 = off0 + s0 - c0;
    unsigned long long p1 = off1 + s1 - c1;

#pragma unroll
    for (int j = 0; j < 8; j++) {
        int stok = tid * 8 + j;
        int e = ids[j];
        int sh = (e & 3) * 16;
        int slot = (int)(((e < 4 ? p0 : p1) >> sh) & 0xFFFFull);
        if (slot < C_) {
            token_slot[e * C_ + slot] = stok;
            gate_slot[e * C_ + slot]  = gate_tok[stok];
        }
        if (e < 4) p0 += 1ull << sh; else p1 += 1ull << sh;
    }
    if (tid == 1023) { tot0s = off0 + s0; tot1s = off1 + s1; }

    float me[8];
#pragma unroll
    for (int e2 = 0; e2 < 8; e2++) me[e2] = 0.f;
#pragma unroll
    for (int j = 0; j < 8; j++) {
        const float* ga = gates_all + (size_t)(tid * 8 + j) * 8;
#pragma unroll
        for (int e2 = 0; e2 < 8; e2++) me[e2] += ga[e2];
    }
#pragma unroll
    for (int e2 = 0; e2 < 8; e2++) red[tid * 8 + e2] = me[e2];
    __syncthreads();
    for (int st = 512; st > 0; st >>= 1) {
        if (tid < st) {
#pragma unroll
            for (int e2 = 0; e2 < 8; e2++) red[tid * 8 + e2] += red[(tid + st) * 8 + e2];
        }
        __syncthreads();
    }
    if (tid == 0) {
        float laux = 0.f;
#pragma unroll
        for (int e2 = 0; e2 < 8; e2++) {
            unsigned long long tv = (e2 < 4) ? tot0s : tot1s;
            float cnt = (float)((tv >> ((e2 & 3) * 16)) & 0xFFFFull);
            laux += red[e2] * cnt;
            out_tail[1 + e2] = cnt;
        }
        out_tail[0] = laux * (8.f / (8192.f * 8192.f));
    }
}

// ---------------- gather dispatched rows (fp32 -> bf16) ----------------
__global__ __launch_bounds__(256)
void gather_kernel(const float* __restrict__ x, const int* __restrict__ token_slot,
                   unsigned short* __restrict__ disp)
{
    int slot = blockIdx.x;
    int tok = token_slot[slot];
    int t = threadIdx.x;
    us8* d = reinterpret_cast<us8*>(disp + (size_t)slot * H_ + t * 8);
    if (tok < 0) {
        us8 z;
#pragma unroll
        for (int i = 0; i < 8; i++) z[i] = 0;
        *d = z;
        return;
    }
    const float4* s4 = (const float4*)(x + (size_t)tok * H_ + t * 8);
    float4 a = s4[0], b = s4[1];
    us8 o;
    o[0] = f2bf(a.x); o[1] = f2bf(a.y); o[2] = f2bf(a.z); o[3] = f2bf(a.w);
    o[4] = f2bf(b.x); o[5] = f2bf(b.y); o[6] = f2bf(b.z); o[7] = f2bf(b.w);
    *d = o;
}

// ================= 256x256 8-phase bf16 GEMM (T2+T3+T4+T5) =================
// A [E*1024][K] row-major bf16, B [E][N][K] bf16 (pre-transposed).
// BM=BN=256, BK=64, 512 thr = 8 waves (2M x 4N). LDS 128 KiB double-buffered.
// LDS half-panel = [8 rowblk][2 colblk][16x32 subtile, st_16x32 XOR swizzle].
// K-tile t: 4 phases, quadrants (lo,lo),(hi,lo),(hi,hi),(lo,hi).
// Stages: P0:H2(t+1) P1:H3(t+1) -> buf^1 ; P2:H0(t+2) P3:H1(t+2) -> buf.
// vmcnt(4) at P3 (vmcnt(0) only on last two tiles).
template<int EPI, int K, int N>
__global__ __launch_bounds__(512, 2)
void gemm8p(const unsigned short* __restrict__ A,
            const unsigned short* __restrict__ B,
            const float* __restrict__ bias,
            unsigned short* __restrict__ hout,
            float* __restrict__ fout,
            const int* __restrict__ token_slot,
            const float* __restrict__ gate_slot,
            int Mt, int Nt)
{
    __shared__ char lds[131072];
    constexpr int KB   = K * 2;        // global row pitch (bytes)
    constexpr int HALF = 128 * KB;     // 128-row half-panel pitch (bytes)
    constexpr int NTI  = K / 64;       // K-tiles

    int nwg = gridDim.x;
    int bid = blockIdx.x;
    int cpx = nwg >> 3;
    int wg  = (bid & 7) * cpx + (bid >> 3);   // XCD-contiguous
    int per_e = Mt * Nt;
    int e  = wg / per_e;
    int r  = wg - e * per_e;
    int nt = r / Mt;
    int mt = r - nt * Mt;

    int tid  = threadIdx.x;
    int lane = tid & 63;
    int wid  = tid >> 6;
    int wr = wid >> 2, wc = wid & 3;

    const char* Ag = (const char*)(A + ((size_t)e * 1024 + (size_t)mt * 256) * (size_t)K);
    const char* Bg = (const char*)(B + ((size_t)e * N    + (size_t)nt * 256) * (size_t)K);

    // staging source offsets (inverse st_16x32 swizzle applied to global src)
    int r16s   = (tid >> 2) & 15;
    int scs    = ((tid & 3) * 16) ^ ((r16s & 8) << 2);
    int colblk = (tid >> 6) & 1;
    int rb0    = tid >> 7;                       // 0..3
    int off0 = (rb0 * 16 + r16s) * KB + colblk * 64 + scs;
    int off1 = off0 + 64 * KB;
    int widb = wid * 1024;

    // swizzled LDS read offset (per lane)
    int lread = (lane & 15) * 64 + (((lane >> 4) * 16) ^ ((lane & 8) << 2));

    auto STAGE = [&](int ldsbase, const char* srcbase) {
        gload16(srcbase + off0, (char*)&lds[ldsbase + widb]);
        gload16(srcbase + off1, (char*)&lds[ldsbase + 8192 + widb]);
    };

    // prologue: tile0 all 4 half-tiles; tile1 H0,H1
    STAGE(0,         Ag);
    STAGE(16384,     Ag + HALF);
    STAGE(32768,     Bg);
    STAGE(49152,     Bg + HALF);
    STAGE(65536,     Ag + 128);
    STAGE(65536 + 16384, Ag + HALF + 128);
    SB(); asm volatile("s_waitcnt vmcnt(4)" ::: "memory"); SB();
    BAR();

    f32x4 acc[8][4];
    f32x4 zv = {0.f, 0.f, 0.f, 0.f};
#pragma unroll
    for (int i = 0; i < 8; i++)
#pragma unroll
        for (int j = 0; j < 4; j++) acc[i][j] = zv;

    int abase_l = wr * 16384 + lread;
    int bbase_l = 32768 + (wc >> 1) * 16384 + (wc & 1) * 8192 + lread;

    for (int t = 0; t < NTI; ++t) {
        int bb  = (t & 1) << 16;
        int ob  = bb ^ 65536;
        const char* ald = lds + bb + abase_l;
        const char* bld = lds + bb + bbase_l;
        bf16x8 alo[4][2], ahi[4][2], blo[2][2], bhi[2][2];

        // ---- P0: read A_lo + B_lo ; stage H2(t+1) ; MFMA (lo,lo) ----
#pragma unroll
        for (int mi = 0; mi < 4; mi++) {
            alo[mi][0] = *(const bf16x8*)(ald + mi * 2048);
            alo[mi][1] = *(const bf16x8*)(ald + mi * 2048 + 1024);
        }
#pragma unroll
        for (int ni = 0; ni < 2; ni++) {
            blo[ni][0] = *(const bf16x8*)(bld + ni * 2048);
            blo[ni][1] = *(const bf16x8*)(bld + ni * 2048 + 1024);
        }
        if (t + 1 < NTI) STAGE(ob + 32768, Bg + (size_t)(t + 1) * 128);
        BAR();
        __builtin_amdgcn_s_setprio(1);
#pragma unroll
        for (int mi = 0; mi < 4; mi++)
#pragma unroll
            for (int ni = 0; ni < 2; ni++) {
                acc[mi][ni] = __builtin_amdgcn_mfma_f32_16x16x32_bf16(alo[mi][0], blo[ni][0], acc[mi][ni], 0, 0, 0);
                acc[mi][ni] = __builtin_amdgcn_mfma_f32_16x16x32_bf16(alo[mi][1], blo[ni][1], acc[mi][ni], 0, 0, 0);
            }
        __builtin_amdgcn_s_setprio(0);
        BAR();

        // ---- P1: read A_hi ; stage H3(t+1) ; MFMA (hi,lo) ----
#pragma unroll
        for (int mi = 0; mi < 4; mi++) {
            ahi[mi][0] = *(const bf16x8*)(ald + 8192 + mi * 2048);
            ahi[mi][1] = *(const bf16x8*)(ald + 8192 + mi * 2048 + 1024);
        }
        if (t + 1 < NTI) STAGE(ob + 49152, Bg + HALF + (size_t)(t + 1) * 128);
        BAR();
        __builtin_amdgcn_s_setprio(1);
#pragma unroll
        for (int mi = 0; mi < 4; mi++)
#pragma unroll
            for (int ni = 0; ni < 2; ni++) {
                acc[mi + 4][ni] = __builtin_amdgcn_mfma_f32_16x16x32_bf16(ahi[mi][0], blo[ni][0], acc[mi + 4][ni], 0, 0, 0);
                acc[mi + 4][ni] = __builtin_amdgcn_mfma_f32_16x16x32_bf16(ahi[mi][1], blo[ni][1], acc[mi + 4][ni], 0, 0, 0);
            }
        __builtin_amdgcn_s_setprio(0);
        BAR();

        // ---- P2: read B_hi ; stage H0(t+2) ; MFMA (hi,hi) ----
#pragma unroll
        for (int ni = 0; ni < 2; ni++) {
            bhi[ni][0] = *(const bf16x8*)(bld + 4096 + ni * 2048);
            bhi[ni][1] = *(const bf16x8*)(bld + 4096 + ni * 2048 + 1024);
        }
        if (t + 2 < NTI) STAGE(bb, Ag + (size_t)(t + 2) * 128);
        BAR();
        __builtin_amdgcn_s_setprio(1);
#pragma unroll
        for (int mi = 0; mi < 4; mi++)
#pragma unroll
            for (int ni = 0; ni < 2; ni++) {
                acc[mi + 4][ni + 2] = __builtin_amdgcn_mfma_f32_16x16x32_bf16(ahi[mi][0], bhi[ni][0], acc[mi + 4][ni + 2], 0, 0, 0);
                acc[mi + 4][ni + 2] = __builtin_amdgcn_mfma_f32_16x16x32_bf16(ahi[mi][1], bhi[ni][1], acc[mi + 4][ni + 2], 0, 0, 0);
            }
        __builtin_amdgcn_s_setprio(0);
        BAR();

        // ---- P3: stage H1(t+2) ; MFMA (lo,hi) ; vmcnt ----
        if (t + 2 < NTI) STAGE(bb + 16384, Ag + HALF + (size_t)(t + 2) * 128);
        BAR();
        __builtin_amdgcn_s_setprio(1);
#pragma unroll
        for (int mi = 0; mi < 4; mi++)
#pragma unroll
            for (int ni = 0; ni < 2; ni++) {
                acc[mi][ni + 2] = __builtin_amdgcn_mfma_f32_16x16x32_bf16(alo[mi][0], bhi[ni][0], acc[mi][ni + 2], 0, 0, 0);
                acc[mi][ni + 2] = __builtin_amdgcn_mfma_f32_16x16x32_bf16(alo[mi][1], bhi[ni][1], acc[mi][ni + 2], 0, 0, 0);
            }
        __builtin_amdgcn_s_setprio(0);
        if (t + 2 < NTI) { SB(); asm volatile("s_waitcnt vmcnt(4)" ::: "memory"); SB(); }
        else             { SB(); asm volatile("s_waitcnt vmcnt(0)" ::: "memory"); SB(); }
        BAR();
    }

    // ---- epilogue ----
    int rbase = wr * 128 + (lane >> 4) * 4;
    int cbase = wc * 64 + (lane & 15);

    if (EPI == 0) {
        size_t rowg = (size_t)e * C_ + (size_t)mt * 256;
        float bb4[4];
#pragma unroll
        for (int ni = 0; ni < 4; ni++)
            bb4[ni] = bias[(size_t)e * N + nt * 256 + cbase + ni * 16];
#pragma unroll
        for (int mi = 0; mi < 8; mi++) {
#pragma unroll
            for (int rr2 = 0; rr2 < 4; rr2++) {
                int m = rbase + mi * 16 + rr2;
                size_t rb = (rowg + (size_t)m) * (size_t)N + nt * 256 + cbase;
#pragma unroll
                for (int ni = 0; ni < 4; ni++) {
                    float v = acc[mi][ni][rr2] + bb4[ni];
                    // gelu(tanh) = v * sigmoid(1.5957691216*(v + 0.044715 v^3))*... = v*sigmoid(2u)
                    float u2 = 1.5957691216057308f * (v + 0.044715f * v * v * v);
                    float gl = v * __frcp_rn(1.f + __expf(-u2));
                    hout[rb + ni * 16] = f2bf(gl);
                }
            }
        }
    } else {
        float bb4[4];
#pragma unroll
        for (int ni = 0; ni < 4; ni++)
            bb4[ni] = bias[(size_t)e * N + nt * 256 + cbase + ni * 16];
#pragma unroll
        for (int mi = 0; mi < 8; mi++) {
#pragma unroll
            for (int rr2 = 0; rr2 < 4; rr2++) {
                int c = mt * 256 + rbase + mi * 16 + rr2;
                int tok = token_slot[e * C_ + c];
                if (tok < 0) continue;
                float g = gate_slot[e * C_ + c];
                size_t rb = (size_t)tok * (size_t)N + nt * 256 + cbase;
#pragma unroll
                for (int ni = 0; ni < 4; ni++) {
                    float v = (acc[mi][ni][rr2] + bb4[ni]) * g;
                    fout[rb + ni * 16] = v;
                }
            }
        }
    }
}

extern "C" void kernel_launch(void* const* d_in, const int* in_sizes, int n_in,
                              void* d_out, int out_size, void* d_ws, size_t ws_size,
                              hipStream_t stream)
{
    const float* x   = (const float*)d_in[0];
    const float* wgp = (const float*)d_in[1];
    const float* w1  = (const float*)d_in[2];
    const float* b1  = (const float*)d_in[3];
    const float* w2  = (const float*)d_in[4];
    const float* b2  = (const float*)d_in[5];
    float* out = (float*)d_out;

    char* ws = (char*)d_ws;
    unsigned short* w1t  = (unsigned short*)(ws);                    // 268435456 B
    unsigned short* w2t  = (unsigned short*)(ws + 268435456ull);     // 268435456 B
    unsigned short* disp = (unsigned short*)(ws + 536870912ull);     //  33554432 B
    unsigned short* hbuf = (unsigned short*)(ws + 570425344ull);     // 134217728 B
    int*   expert_id  = (int*)  (ws + 704643072ull);
    float* gate_tok   = (float*)(ws + 704675840ull);
    float* gates_all  = (float*)(ws + 704708608ull);
    int*   token_slot = (int*)  (ws + 704970752ull);
    float* gate_slot  = (float*)(ws + 705003520ull);

    zero_kernel<<<4096, 256, 0, stream>>>(out, out_size);
    transpose_cvt<<<8 * 32 * 128, 256, 0, stream>>>(w1, w1t, 2048, 8192);
    transpose_cvt<<<8 * 128 * 32, 256, 0, stream>>>(w2, w2t, 8192, 2048);
    gating_kernel<<<2048, 256, 0, stream>>>(x, wgp, expert_id, gate_tok, gates_all);
    scan_kernel<<<1, 1024, 0, stream>>>(expert_id, gate_tok, gates_all, token_slot, gate_slot, out + OUTN);
    gather_kernel<<<8192, 256, 0, stream>>>(x, token_slot, disp);
    gemm8p<0, 2048, 8192><<<1024, 512, 0, stream>>>(disp, w1t, b1, hbuf, nullptr, nullptr, nullptr, 4, 32);
    gemm8p<1, 8192, 2048><<<256, 512, 0, stream>>>(hbuf, w2t, b2, nullptr, out, token_slot, gate_slot, 4, 8);
}